// Round 12
// baseline (87.895 us; speedup 1.0000x reference)
//
#include <hip/hip_runtime.h>
#include <math.h>

#define KROOTS 16
#define NC 17        // K+1 coefficients
#define BLK 64       // one wave per block
#define NCOMP_REP 20 // INSTRUMENTATION: repeat Vieta compute to measure VALU slope

// Opaque chain: "may modify" v, CONSUMES dep -> the producer of dep (the whole
// previous rep's recurrence) stays live. Fixes R11's DCE hole.
__device__ __forceinline__ float opaque_chain(float v, float dep) {
    asm volatile("" : "+v"(v) : "v"(dep));
    return v;
}

// Real-parts-only output (17 floats/row), per-wave LDS store staging.
// INSTRUMENTATION ROUND 3b: compute repeated NCOMP_REP times with a live
// scale->next-rep dependency chain so no rep is dead. Single store pass.
template <int MODE>
__global__ __launch_bounds__(BLK) void encoder_vieta_kernel(
    const float* __restrict__ x,
    const float* __restrict__ shuffle,
    float* __restrict__ out,
    int B)
{
    __shared__ float sc[KROOTS], ss[KROOTS];
    __shared__ float so[BLK * NC];   // 4,352 B per-wave store staging

    const int tid = threadIdx.x;
    if (tid < KROOTS) {
        float phi = shuffle[tid];
        sc[tid] = cosf(phi);
        ss[tid] = sinf(phi);
    }
    __syncthreads();

    const int b = blockIdx.x * BLK + tid;
    if (b >= B) return;

    // R = sqrt(1 + sin(pi/16)) (learnable_radius=False)
    const float R    = 1.09320186720915563f;
    const float invR = 0.91474476120342423f;

    const float4* xp = reinterpret_cast<const float4*>(x + (size_t)b * KROOTS);
    float xr[KROOTS];
    #pragma unroll
    for (int i = 0; i < 4; ++i) {
        float4 v = xp[i];
        xr[4 * i + 0] = v.x;
        xr[4 * i + 1] = v.y;
        xr[4 * i + 2] = v.z;
        xr[4 * i + 3] = v.w;
    }

    float cr[NC], ci[NC];
    float scale = 0.0f;

    // Each rep: asm consumes previous rep's scale (side effect -> live chain),
    // so all NCOMP_REP recurrences are really executed and serialized.
    #pragma unroll 1
    for (int rep = 0; rep < NCOMP_REP; ++rep) {
        xr[0] = opaque_chain(xr[0], scale);

        cr[0] = 1.0f; ci[0] = 0.0f;
        #pragma unroll
        for (int d = 1; d < NC; ++d) { cr[d] = 0.0f; ci[d] = 0.0f; }

        #pragma unroll
        for (int j = 0; j < KROOTS; ++j) {
            const float rad = (xr[j] > 0.0f) ? R : invR;
            const float rr = rad * sc[j];
            const float ri = rad * ss[j];
            #pragma unroll
            for (int d = j + 1; d >= 1; --d) {
                const float ar = cr[d - 1], ai = ci[d - 1];
                cr[d] = fmaf(-rr, ar, fmaf( ri, ai, cr[d]));
                ci[d] = fmaf(-rr, ai, fmaf(-ri, ar, ci[d]));
            }
        }

        float sum = 0.0f;
        #pragma unroll
        for (int d = 0; d < NC; ++d)
            sum = fmaf(cr[d], cr[d], fmaf(ci[d], ci[d], sum));
        scale = sqrtf(17.0f) * __frsqrt_rn(sum);
    }

    if (MODE == 0) {
        float2* op = reinterpret_cast<float2*>(out + (size_t)b * 2 * NC);
        #pragma unroll
        for (int d = 0; d < NC; ++d)
            op[d] = make_float2(cr[d] * scale, ci[d] * scale);
    } else {
        // stage real parts: stride 17 floats (odd -> 2 lanes/bank, free)
        #pragma unroll
        for (int d = 0; d < NC; ++d)
            so[tid * NC + d] = cr[d] * scale;
        __syncthreads();

        const size_t blk_f4 = (size_t)blockIdx.x * (BLK * NC / 4);
        float4* og = reinterpret_cast<float4*>(out) + blk_f4;
        const float4* sg = reinterpret_cast<const float4*>(so);
        #pragma unroll
        for (int i = tid; i < BLK * NC / 4; i += BLK)   // 272 f4 -> 4.25/thread
            og[i] = sg[i];
    }
}

extern "C" void kernel_launch(void* const* d_in, const int* in_sizes, int n_in,
                              void* d_out, int out_size, void* d_ws, size_t ws_size,
                              hipStream_t stream) {
    const float* x       = (const float*)d_in[0];
    const float* shuffle = (const float*)d_in[1];
    float* out = (float*)d_out;
    const int B = in_sizes[0] / KROOTS;
    const int grid = (B + BLK - 1) / BLK;
    if (out_size >= 2 * NC * B) {
        encoder_vieta_kernel<0><<<grid, BLK, 0, stream>>>(x, shuffle, out, B);
    } else {
        encoder_vieta_kernel<1><<<grid, BLK, 0, stream>>>(x, shuffle, out, B);
    }
}

// Round 13
// 23.572 us; speedup vs baseline: 3.7288x; 3.7288x over previous
//
#include <hip/hip_runtime.h>
#include <math.h>

#define KROOTS 16
#define NC 17                 // K+1 coefficients
#define BLK 64                // one wave per block
#define TROW 20               // table row stride in floats (80 B, float4-aligned)
#define TENT 65536            // 2^16 sign patterns
#define TBYTES ((size_t)TENT * TROW * sizeof(float))

// R = sqrt(1 + sin(pi/16)) (learnable_radius=False)
#define RAD_P 1.09320186720915563f
#define RAD_N 0.91474476120342423f

// ---------- Kernel 1: build normalized coefficient table ----------
// Thread t computes the output row for sign pattern t (bit j set = x[j] > 0).
// LDS-staged so the 4.4 MB table write is coalesced.
__global__ __launch_bounds__(BLK) void build_table_kernel(
    const float* __restrict__ shuffle,
    float* __restrict__ table)
{
    __shared__ float sc[KROOTS], ss[KROOTS];
    __shared__ float so[BLK * TROW];   // 5,120 floats = 20 KB staging

    const int tid = threadIdx.x;
    if (tid < KROOTS) {
        float phi = shuffle[tid];
        sc[tid] = cosf(phi);
        ss[tid] = sinf(phi);
    }
    __syncthreads();

    const unsigned idx = blockIdx.x * BLK + tid;   // 0..65535 = sign pattern

    float cr[NC], ci[NC];
    cr[0] = 1.0f; ci[0] = 0.0f;
    #pragma unroll
    for (int d = 1; d < NC; ++d) { cr[d] = 0.0f; ci[d] = 0.0f; }

    #pragma unroll
    for (int j = 0; j < KROOTS; ++j) {
        const float rad = ((idx >> j) & 1u) ? RAD_P : RAD_N;
        const float rr = rad * sc[j];
        const float ri = rad * ss[j];
        #pragma unroll
        for (int d = j + 1; d >= 1; --d) {
            const float ar = cr[d - 1], ai = ci[d - 1];
            cr[d] = fmaf(-rr, ar, fmaf( ri, ai, cr[d]));
            ci[d] = fmaf(-rr, ai, fmaf(-ri, ar, ci[d]));
        }
    }

    float sum = 0.0f;
    #pragma unroll
    for (int d = 0; d < NC; ++d)
        sum = fmaf(cr[d], cr[d], fmaf(ci[d], ci[d], sum));
    const float scale = sqrtf(17.0f) * __frsqrt_rn(sum);

    // stage row (stride 20: 8-way bank alias on writes, negligible at 1024 blocks)
    #pragma unroll
    for (int d = 0; d < NC; ++d)
        so[tid * TROW + d] = cr[d] * scale;
    #pragma unroll
    for (int d = NC; d < TROW; ++d)
        so[tid * TROW + d] = 0.0f;     // deterministic pad
    __syncthreads();

    // cooperative contiguous float4 store: 320 f4 per block
    float4* og = reinterpret_cast<float4*>(table + (size_t)blockIdx.x * BLK * TROW);
    const float4* sg = reinterpret_cast<const float4*>(so);
    #pragma unroll
    for (int i = tid; i < BLK * TROW / 4; i += BLK)
        og[i] = sg[i];
}

// ---------- Kernel 2: sign-extract + table gather + coalesced write ----------
__global__ __launch_bounds__(BLK) void gather_kernel(
    const float* __restrict__ x,
    const float* __restrict__ table,
    float* __restrict__ out,
    int B)
{
    __shared__ float so[BLK * NC];     // 4,352 B store staging

    const int tid = threadIdx.x;
    const size_t b = (size_t)blockIdx.x * BLK + tid;

    // load row's 16 floats (4x float4), build 16-bit sign index
    const float4* xp = reinterpret_cast<const float4*>(x + b * KROOTS);
    unsigned idx = 0;
    #pragma unroll
    for (int i = 0; i < 4; ++i) {
        float4 v = xp[i];
        idx |= (v.x > 0.0f ? 1u : 0u) << (4 * i + 0);
        idx |= (v.y > 0.0f ? 1u : 0u) << (4 * i + 1);
        idx |= (v.z > 0.0f ? 1u : 0u) << (4 * i + 2);
        idx |= (v.w > 0.0f ? 1u : 0u) << (4 * i + 3);
    }

    // gather 80 B row from table (L2/L3-resident, 5x float4)
    const float4* row = reinterpret_cast<const float4*>(table + (size_t)idx * TROW);
    float4 r0 = row[0], r1 = row[1], r2 = row[2], r3 = row[3], r4 = row[4];

    // stage 17 floats (stride 17: odd -> conflict-free)
    float* s = so + tid * NC;
    s[0]=r0.x; s[1]=r0.y; s[2]=r0.z; s[3]=r0.w;
    s[4]=r1.x; s[5]=r1.y; s[6]=r1.z; s[7]=r1.w;
    s[8]=r2.x; s[9]=r2.y; s[10]=r2.z; s[11]=r2.w;
    s[12]=r3.x; s[13]=r3.y; s[14]=r3.z; s[15]=r3.w;
    s[16]=r4.x;
    __syncthreads();

    // cooperative contiguous float4 store of block's 4,352 B
    float4* og = reinterpret_cast<float4*>(out) +
                 (size_t)blockIdx.x * (BLK * NC / 4);
    const float4* sg = reinterpret_cast<const float4*>(so);
    #pragma unroll
    for (int i = tid; i < BLK * NC / 4; i += BLK)
        og[i] = sg[i];
}

// ---------- Fallback: direct per-thread Vieta (R7 kernel) ----------
// MODE 0: interleaved (re,im); MODE 1: real parts only.
template <int MODE>
__global__ __launch_bounds__(BLK) void encoder_vieta_kernel(
    const float* __restrict__ x,
    const float* __restrict__ shuffle,
    float* __restrict__ out,
    int B)
{
    __shared__ float sc[KROOTS], ss[KROOTS];
    __shared__ float so[BLK * NC];

    const int tid = threadIdx.x;
    if (tid < KROOTS) {
        float phi = shuffle[tid];
        sc[tid] = cosf(phi);
        ss[tid] = sinf(phi);
    }
    __syncthreads();

    const int b = blockIdx.x * BLK + tid;
    if (b >= B) return;

    const float4* xp = reinterpret_cast<const float4*>(x + (size_t)b * KROOTS);
    float xr[KROOTS];
    #pragma unroll
    for (int i = 0; i < 4; ++i) {
        float4 v = xp[i];
        xr[4 * i + 0] = v.x;
        xr[4 * i + 1] = v.y;
        xr[4 * i + 2] = v.z;
        xr[4 * i + 3] = v.w;
    }

    float cr[NC], ci[NC];
    cr[0] = 1.0f; ci[0] = 0.0f;
    #pragma unroll
    for (int d = 1; d < NC; ++d) { cr[d] = 0.0f; ci[d] = 0.0f; }

    #pragma unroll
    for (int j = 0; j < KROOTS; ++j) {
        const float rad = (xr[j] > 0.0f) ? RAD_P : RAD_N;
        const float rr = rad * sc[j];
        const float ri = rad * ss[j];
        #pragma unroll
        for (int d = j + 1; d >= 1; --d) {
            const float ar = cr[d - 1], ai = ci[d - 1];
            cr[d] = fmaf(-rr, ar, fmaf( ri, ai, cr[d]));
            ci[d] = fmaf(-rr, ai, fmaf(-ri, ar, ci[d]));
        }
    }

    float sum = 0.0f;
    #pragma unroll
    for (int d = 0; d < NC; ++d)
        sum = fmaf(cr[d], cr[d], fmaf(ci[d], ci[d], sum));
    const float scale = sqrtf(17.0f) * __frsqrt_rn(sum);

    if (MODE == 0) {
        float2* op = reinterpret_cast<float2*>(out + (size_t)b * 2 * NC);
        #pragma unroll
        for (int d = 0; d < NC; ++d)
            op[d] = make_float2(cr[d] * scale, ci[d] * scale);
    } else {
        #pragma unroll
        for (int d = 0; d < NC; ++d)
            so[tid * NC + d] = cr[d] * scale;
        __syncthreads();
        float4* og = reinterpret_cast<float4*>(out) +
                     (size_t)blockIdx.x * (BLK * NC / 4);
        const float4* sg = reinterpret_cast<const float4*>(so);
        #pragma unroll
        for (int i = tid; i < BLK * NC / 4; i += BLK)
            og[i] = sg[i];
    }
}

extern "C" void kernel_launch(void* const* d_in, const int* in_sizes, int n_in,
                              void* d_out, int out_size, void* d_ws, size_t ws_size,
                              hipStream_t stream) {
    const float* x       = (const float*)d_in[0];
    const float* shuffle = (const float*)d_in[1];
    float* out = (float*)d_out;
    const int B = in_sizes[0] / KROOTS;
    const int grid = (B + BLK - 1) / BLK;

    if (out_size >= 2 * NC * B) {
        // interleaved complex layout (not observed in practice)
        encoder_vieta_kernel<0><<<grid, BLK, 0, stream>>>(x, shuffle, out, B);
    } else if (ws_size >= TBYTES) {
        float* table = (float*)d_ws;
        build_table_kernel<<<TENT / BLK, BLK, 0, stream>>>(shuffle, table);
        gather_kernel<<<grid, BLK, 0, stream>>>(x, table, out, B);
    } else {
        encoder_vieta_kernel<1><<<grid, BLK, 0, stream>>>(x, shuffle, out, B);
    }
}

// Round 14
// 12.576 us; speedup vs baseline: 6.9894x; 1.8744x over previous
//
#include <hip/hip_runtime.h>
#include <math.h>

#define KROOTS 16
#define NC 17
#define BLK 256

// R = sqrt(1 + sin(pi/16)) (learnable_radius=False)
#define RAD_P 1.09320186720915563f
#define RAD_N 0.91474476120342423f

typedef float v2f __attribute__((ext_vector_type(2)));

// c += (-r) * p, complex; rv=(rr,rr), iv=(ri,ri), p=(pr,pi), c=(cr,ci).
// step1: c += (-rr)*p           -> cr -= rr*pr ; ci -= rr*pi
// step2: c += (ri*pi, -ri*pr)   -> op_sel swaps p for both halves, neg_hi on a
__device__ __forceinline__ void cfma_neg(v2f& c, v2f rv, v2f iv, v2f p) {
    asm("v_pk_fma_f32 %0, %1, %2, %0 neg_lo:[1,0,0] neg_hi:[1,0,0]"
        : "+v"(c) : "v"(rv), "v"(p));
    asm("v_pk_fma_f32 %0, %1, %2, %0 op_sel:[0,1,0] op_sel_hi:[1,0,1] neg_hi:[1,0,0]"
        : "+v"(c) : "v"(iv), "v"(p));
}

// c = (-r) * p  (new leading coefficient; replaces fma-into-zero + init movs)
__device__ __forceinline__ v2f cmul_neg(v2f rv, v2f iv, v2f p) {
    v2f c;
    asm("v_pk_mul_f32 %0, %1, %2 neg_lo:[1,0,0] neg_hi:[1,0,0]"
        : "=v"(c) : "v"(rv), "v"(p));
    asm("v_pk_fma_f32 %0, %1, %2, %0 op_sel:[0,1,0] op_sel_hi:[1,0,1] neg_hi:[1,0,0]"
        : "+v"(c) : "v"(iv), "v"(p));
    return c;
}

// MODE 0: interleaved (re,im) fallback; MODE 1: real parts only (observed layout)
template <int MODE>
__global__ __launch_bounds__(BLK) void encoder_vieta_pk(
    const float* __restrict__ x,
    const float* __restrict__ shuffle,
    float* __restrict__ out,
    int B)
{
    __shared__ v2f scc[KROOTS], ssc[KROOTS];   // (cos,cos), (sin,sin) pairs
    __shared__ float so[BLK * NC];             // 17,408 B store staging

    const int tid = threadIdx.x;
    if (tid < KROOTS) {                        // only wave 0 pays cosf/sinf
        float phi = shuffle[tid];
        float cv = cosf(phi), sv = sinf(phi);
        scc[tid] = (v2f){cv, cv};
        ssc[tid] = (v2f){sv, sv};
    }
    __syncthreads();

    const size_t b = (size_t)blockIdx.x * BLK + tid;   // B % 256 == 0

    // row load: 4x float4 (64 B/thread)
    const float4* xp = reinterpret_cast<const float4*>(x + b * KROOTS);
    float xr[KROOTS];
    #pragma unroll
    for (int i = 0; i < 4; ++i) {
        float4 v = xp[i];
        xr[4 * i + 0] = v.x;
        xr[4 * i + 1] = v.y;
        xr[4 * i + 2] = v.z;
        xr[4 * i + 3] = v.w;
    }

    const v2f Rv  = (v2f){RAD_P, RAD_P};
    const v2f Iv  = (v2f){RAD_N, RAD_N};

    // Vieta with packed complex FMAs. c[0] = 1 stays constant.
    v2f c[NC];
    c[0] = (v2f){1.0f, 0.0f};
    #pragma unroll
    for (int j = 0; j < KROOTS; ++j) {
        const v2f radv = (xr[j] > 0.0f) ? Rv : Iv;   // cmp + 2 cndmask
        const v2f rv = radv * scc[j];                // pk mul
        const v2f iv = radv * ssc[j];
        c[j + 1] = cmul_neg(rv, iv, c[j]);           // new coefficient
        #pragma unroll
        for (int d = j; d >= 1; --d)                 // descending: c[d-1] pre-update
            cfma_neg(c[d], rv, iv, c[d - 1]);
    }

    // L2 norm over complex magnitudes; target norm sqrt(17)
    v2f s2 = c[0] * c[0];
    #pragma unroll
    for (int d = 1; d < NC; ++d)
        s2 = c[d] * c[d] + s2;
    const float scale = sqrtf(17.0f) * __frsqrt_rn(s2.x + s2.y);

    if (MODE == 0) {
        float2* op = reinterpret_cast<float2*>(out + b * 2 * NC);
        #pragma unroll
        for (int d = 0; d < NC; ++d)
            op[d] = make_float2(c[d].x * scale, c[d].y * scale);
    } else {
        // stage real parts: stride 17 floats (odd -> conflict-free)
        #pragma unroll
        for (int d = 0; d < NC; ++d)
            so[tid * NC + d] = c[d].x * scale;
        __syncthreads();

        // cooperative contiguous float4 store: 1088 f4 for the block's 17,408 B
        float4* og = reinterpret_cast<float4*>(out) +
                     (size_t)blockIdx.x * (BLK * NC / 4);
        const float4* sg = reinterpret_cast<const float4*>(so);
        #pragma unroll
        for (int i = tid; i < BLK * NC / 4; i += BLK)
            og[i] = sg[i];
    }
}

extern "C" void kernel_launch(void* const* d_in, const int* in_sizes, int n_in,
                              void* d_out, int out_size, void* d_ws, size_t ws_size,
                              hipStream_t stream) {
    const float* x       = (const float*)d_in[0];
    const float* shuffle = (const float*)d_in[1];
    float* out = (float*)d_out;
    const int B = in_sizes[0] / KROOTS;
    const int grid = (B + BLK - 1) / BLK;
    if (out_size >= 2 * NC * B) {
        encoder_vieta_pk<0><<<grid, BLK, 0, stream>>>(x, shuffle, out, B);
    } else {
        encoder_vieta_pk<1><<<grid, BLK, 0, stream>>>(x, shuffle, out, B);
    }
}